// Round 1
// baseline (21507.945 us; speedup 1.0000x reference)
//
#include <hip/hip_runtime.h>
#include <hip/hip_bf16.h>

#define SEQL  2048
#define IND   256
#define MEMD  512
#define G4    2048   // 4*MEMD gate rows
#define NWG   16     // workgroups per sequence
#define VOCABN 100000

// ---------- bf16 helpers (bit-level, round-nearest-even) ----------
__device__ __forceinline__ unsigned short f2bf(float f) {
  unsigned u = __float_as_uint(f);
  u += 0x7fffu + ((u >> 16) & 1u);
  return (unsigned short)(u >> 16);
}
__device__ __forceinline__ float bf2f(unsigned b) {
  return __uint_as_float(b << 16);
}

// ---------- init: zero the h publication buffer ----------
// hbuf layout: [seq][parity][512] u32 words, word = (epoch<<16) | bf16(h)
__global__ void init_k(unsigned* __restrict__ hbuf) {
  int i = blockIdx.x * blockDim.x + threadIdx.x;
  if (i < 2 * 2 * MEMD) hbuf[i] = 0u;   // epoch 0, h = 0
}

// ---------- xp GEMM: xp[s][t][perm(n)] = emb[ids[t]] . W_ih[n] + b ----------
// grid (32 t-tiles, 32 n-tiles, 2 seq), block 256. 64x64 tile, K chunked by 64.
// LDS is k-major [k][row] so compute reads are conflict-free float4.
__global__ __launch_bounds__(256) void xp_gemm(
    const int* __restrict__ lin, const int* __restrict__ rin,
    const float* __restrict__ emb, const float* __restrict__ W_ih,
    const float* __restrict__ b_ih, const float* __restrict__ b_hh,
    unsigned short* __restrict__ xp) {
  __shared__ float As[64][68];
  __shared__ float Bs[64][68];
  const int s = blockIdx.z;
  const int* ids = (s == 0) ? lin : rin;
  const int t0 = blockIdx.x * 64;
  const int n0 = blockIdx.y * 64;
  const int tid = threadIdx.x;
  const int tx = tid & 15, ty = tid >> 4;

  float acc[4][4];
#pragma unroll
  for (int i = 0; i < 4; ++i)
#pragma unroll
    for (int j = 0; j < 4; ++j) acc[i][j] = 0.f;

  for (int kc = 0; kc < IND; kc += 64) {
#pragma unroll
    for (int j = 0; j < 4; ++j) {
      int fi  = tid + 256 * j;       // 0..1023 float4 slots
      int row = fi >> 4;             // 0..63
      int c4  = fi & 15;             // float4 index within 64 k
      int id  = ids[t0 + row];
      id = max(0, min(id, VOCABN - 1));
      const float4 va = *(const float4*)(emb + (size_t)id * IND + kc + c4 * 4);
      As[c4 * 4 + 0][row] = va.x; As[c4 * 4 + 1][row] = va.y;
      As[c4 * 4 + 2][row] = va.z; As[c4 * 4 + 3][row] = va.w;
      const float4 vb = *(const float4*)(W_ih + (size_t)(n0 + row) * IND + kc + c4 * 4);
      Bs[c4 * 4 + 0][row] = vb.x; Bs[c4 * 4 + 1][row] = vb.y;
      Bs[c4 * 4 + 2][row] = vb.z; Bs[c4 * 4 + 3][row] = vb.w;
    }
    __syncthreads();
#pragma unroll 8
    for (int k = 0; k < 64; ++k) {
      const float4 a = *(const float4*)&As[k][tx * 4];
      const float4 b = *(const float4*)&Bs[k][ty * 4];
      acc[0][0] = fmaf(a.x, b.x, acc[0][0]); acc[0][1] = fmaf(a.x, b.y, acc[0][1]);
      acc[0][2] = fmaf(a.x, b.z, acc[0][2]); acc[0][3] = fmaf(a.x, b.w, acc[0][3]);
      acc[1][0] = fmaf(a.y, b.x, acc[1][0]); acc[1][1] = fmaf(a.y, b.y, acc[1][1]);
      acc[1][2] = fmaf(a.y, b.z, acc[1][2]); acc[1][3] = fmaf(a.y, b.w, acc[1][3]);
      acc[2][0] = fmaf(a.z, b.x, acc[2][0]); acc[2][1] = fmaf(a.z, b.y, acc[2][1]);
      acc[2][2] = fmaf(a.z, b.z, acc[2][2]); acc[2][3] = fmaf(a.z, b.w, acc[2][3]);
      acc[3][0] = fmaf(a.w, b.x, acc[3][0]); acc[3][1] = fmaf(a.w, b.y, acc[3][1]);
      acc[3][2] = fmaf(a.w, b.z, acc[3][2]); acc[3][3] = fmaf(a.w, b.w, acc[3][3]);
    }
    __syncthreads();
  }
  // epilogue: add bias, permute rows so each recurrent WG's 128 values are contiguous
#pragma unroll
  for (int ri = 0; ri < 4; ++ri) {
#pragma unroll
    for (int bj = 0; bj < 4; ++bj) {
      int t = t0 + tx * 4 + ri;
      int n = n0 + ty * 4 + bj;
      float v = acc[ri][bj] + b_ih[n] + b_hh[n];
      int w = (n & 511) >> 5;     // owning WG
      int gate = n >> 9;          // 0..3 (i,f,g,o)
      int hd = n & 31;            // local h dim
      int pos = w * 128 + gate * 32 + hd;
      xp[((size_t)s * SEQL + t) * G4 + pos] = f2bf(v);
    }
  }
}

// ---------- persistent recurrent kernel ----------
// 32 blocks x 512 threads. block -> (seq = blk&1, w = blk>>1).
// Each WG owns h dims [32w, 32w+32) = 128 gate rows; W_hh slice in VGPRs.
// Per-step sync: h words self-describe with a 16-bit epoch; parity double-buffer.
__global__ __launch_bounds__(512) void lstm_rec(
    const float* __restrict__ W_hh,
    const unsigned short* __restrict__ xp,
    unsigned* __restrict__ hbuf) {
  __shared__ float g_lds[2][128];
  const int blk = blockIdx.x;
  const int s = blk & 1;
  const int w = blk >> 1;          // 0..15
  const int tid = threadIdx.x;
  const int cg = tid & 15;         // k chunk group (32 k each)
  const int rg = tid >> 4;         // row group (4 rows each), 0..31

  // load W_hh slice into registers: rows r = rg*4+ri (local), k = cg*32..+32
  float wreg[4][32];
#pragma unroll
  for (int ri = 0; ri < 4; ++ri) {
    int r = rg * 4 + ri;           // 0..127
    int gate = r >> 5, hd = r & 31;
    const float* src = W_hh + ((size_t)gate * MEMD + w * 32 + hd) * MEMD + cg * 32;
#pragma unroll
    for (int q = 0; q < 8; ++q) {
      const float4 v = *(const float4*)(src + q * 4);
      wreg[ri][q * 4 + 0] = v.x; wreg[ri][q * 4 + 1] = v.y;
      wreg[ri][q * 4 + 2] = v.z; wreg[ri][q * 4 + 3] = v.w;
    }
  }

  unsigned* hbase = hbuf + s * (2 * MEMD);
  const unsigned short* xq0 = xp + (size_t)s * SEQL * G4 + w * 128;
  float cst = 0.f;                 // cell state for h-dim `tid` (only tid<32 uses it)

  for (int t = 0; t < SEQL; ++t) {
    // prefetch this step's xp for the gate threads (independent of h -> hides latency)
    float xg0 = 0.f, xg1 = 0.f, xg2 = 0.f, xg3 = 0.f;
    if (tid < 32) {
      const unsigned short* xq = xq0 + (size_t)t * G4;
      xg0 = bf2f(xq[tid]);
      xg1 = bf2f(xq[32 + tid]);
      xg2 = bf2f(xq[64 + tid]);
      xg3 = bf2f(xq[96 + tid]);
    }

    // ---- poll h_t (epoch == t) on the parity-t buffer ----
    const unsigned* hr = hbase + (t & 1) * MEMD;
    unsigned uw[32];
#pragma unroll
    for (int kk = 0; kk < 32; ++kk)
      uw[kk] = __hip_atomic_load(hr + cg * 32 + kk, __ATOMIC_RELAXED, __HIP_MEMORY_SCOPE_AGENT);
    {
      const unsigned want = (unsigned)t;
      bool again = true;
      int guard = 0;
      while (again) {
        again = false;
#pragma unroll
        for (int kk = 0; kk < 32; ++kk) {
          if ((uw[kk] >> 16) != want) {
            uw[kk] = __hip_atomic_load(hr + cg * 32 + kk, __ATOMIC_RELAXED, __HIP_MEMORY_SCOPE_AGENT);
            again = true;
          }
        }
        if (++guard > (1 << 20)) break;   // safety valve: never hang the harness
      }
    }
    float hreg[32];
#pragma unroll
    for (int kk = 0; kk < 32; ++kk) hreg[kk] = bf2f(uw[kk] & 0xffffu);

    // ---- partial dot products: 4 rows x 32 k ----
    float part[4] = {0.f, 0.f, 0.f, 0.f};
#pragma unroll
    for (int kk = 0; kk < 32; ++kk) {
#pragma unroll
      for (int ri = 0; ri < 4; ++ri)
        part[ri] = fmaf(wreg[ri][kk], hreg[kk], part[ri]);
    }
    // reduce across the 16 cg lanes (same rg -> consecutive lanes in a wave)
#pragma unroll
    for (int m = 8; m >= 1; m >>= 1) {
#pragma unroll
      for (int ri = 0; ri < 4; ++ri)
        part[ri] += __shfl_xor(part[ri], m, 64);
    }
    if (cg == 0) {
#pragma unroll
      for (int ri = 0; ri < 4; ++ri) g_lds[t & 1][rg * 4 + ri] = part[ri];
    }
    __syncthreads();

    // ---- gate math + publish h_{t+1} (epoch t+1, parity t+1) ----
    if (tid < 32) {
      const float* gl = g_lds[t & 1];
      float gi = gl[tid] + xg0;
      float gf = gl[32 + tid] + xg1;
      float gg = gl[64 + tid] + xg2;
      float go = gl[96 + tid] + xg3;
      float i_ = 1.f / (1.f + __expf(-gi));
      float f_ = 1.f / (1.f + __expf(-gf));
      float ggc = fminf(fmaxf(gg, -15.f), 15.f);
      float e2 = __expf(-2.f * ggc);
      float g_ = (1.f - e2) / (1.f + e2);
      float o_ = 1.f / (1.f + __expf(-go));
      cst = f_ * cst + i_ * g_;
      float cc = fminf(fmaxf(cst, -15.f), 15.f);
      float e2c = __expf(-2.f * cc);
      float th = (1.f - e2c) / (1.f + e2c);
      float h_ = o_ * th;
      unsigned word = (((unsigned)(t + 1)) << 16) | (unsigned)f2bf(h_);
      __hip_atomic_store(hbase + ((t + 1) & 1) * MEMD + w * 32 + tid, word,
                         __ATOMIC_RELAXED, __HIP_MEMORY_SCOPE_AGENT);
    }
  }
}

// ---------- final reduction: out = exp(-sum |lh - rh|) ----------
__global__ __launch_bounds__(512) void finish_k(const unsigned* __restrict__ hbuf,
                                                float* __restrict__ out) {
  const int tid = threadIdx.x;   // 512 threads, epoch 2048 lives in parity-0 buffers
  float l = bf2f(hbuf[tid] & 0xffffu);
  float r = bf2f(hbuf[2 * MEMD + tid] & 0xffffu);
  float d = fabsf(l - r);
#pragma unroll
  for (int m = 32; m >= 1; m >>= 1) d += __shfl_xor(d, m, 64);
  __shared__ float wsum[8];
  if ((tid & 63) == 0) wsum[tid >> 6] = d;
  __syncthreads();
  if (tid == 0) {
    float sum = 0.f;
#pragma unroll
    for (int i = 0; i < 8; ++i) sum += wsum[i];
    out[0] = expf(-sum);
  }
}

extern "C" void kernel_launch(void* const* d_in, const int* in_sizes, int n_in,
                              void* d_out, int out_size, void* d_ws, size_t ws_size,
                              hipStream_t stream) {
  const int*   lin  = (const int*)d_in[0];
  const int*   rin  = (const int*)d_in[1];
  const float* emb  = (const float*)d_in[2];
  const float* W_ih = (const float*)d_in[3];
  const float* W_hh = (const float*)d_in[4];
  const float* b_ih = (const float*)d_in[5];
  const float* b_hh = (const float*)d_in[6];
  float* out = (float*)d_out;

  // workspace layout: xp bf16 [2][2048][2048] (16 MiB), then hbuf [2][2][512] u32 (8 KiB)
  unsigned char* ws = (unsigned char*)d_ws;
  unsigned short* xp = (unsigned short*)ws;
  unsigned* hbuf = (unsigned*)(ws + (size_t)2 * SEQL * G4 * sizeof(unsigned short));

  hipLaunchKernelGGL(init_k, dim3(2), dim3(1024), 0, stream, hbuf);
  hipLaunchKernelGGL(xp_gemm, dim3(SEQL / 64, G4 / 64, 2), dim3(256), 0, stream,
                     lin, rin, emb, W_ih, b_ih, b_hh, xp);
  hipLaunchKernelGGL(lstm_rec, dim3(2 * NWG), dim3(512), 0, stream, W_hh, xp, hbuf);
  hipLaunchKernelGGL(finish_k, dim3(1), dim3(512), 0, stream, hbuf, out);
}

// Round 2
// 4195.592 us; speedup vs baseline: 5.1263x; 5.1263x over previous
//
#include <hip/hip_runtime.h>
#include <hip/hip_bf16.h>

#define SEQL  2048
#define IND   256
#define MEMD  512
#define G4    2048   // 4*MEMD gate rows
#define NWG   16     // workgroups per sequence
#define VOCABN 100000

// ---------- bf16 helpers (bit-level, round-nearest-even) ----------
__device__ __forceinline__ unsigned short f2bf(float f) {
  unsigned u = __float_as_uint(f);
  u += 0x7fffu + ((u >> 16) & 1u);
  return (unsigned short)(u >> 16);
}
__device__ __forceinline__ float bf2f(unsigned b) {
  return __uint_as_float(b << 16);
}

// ---------- init: zero the h publication buffer ----------
// hbuf layout: [seq][parity][512] u32 words, word = (epoch<<16) | bf16(h)
__global__ void init_k(unsigned* __restrict__ hbuf) {
  int i = blockIdx.x * blockDim.x + threadIdx.x;
  if (i < 2 * 2 * MEMD) hbuf[i] = 0u;   // epoch 0, h = 0
}

// ---------- xp GEMM: xp[s][t][perm(n)] = emb[ids[t]] . W_ih[n] + b ----------
__global__ __launch_bounds__(256) void xp_gemm(
    const int* __restrict__ lin, const int* __restrict__ rin,
    const float* __restrict__ emb, const float* __restrict__ W_ih,
    const float* __restrict__ b_ih, const float* __restrict__ b_hh,
    unsigned short* __restrict__ xp) {
  __shared__ float As[64][68];
  __shared__ float Bs[64][68];
  const int s = blockIdx.z;
  const int* ids = (s == 0) ? lin : rin;
  const int t0 = blockIdx.x * 64;
  const int n0 = blockIdx.y * 64;
  const int tid = threadIdx.x;
  const int tx = tid & 15, ty = tid >> 4;

  float acc[4][4];
#pragma unroll
  for (int i = 0; i < 4; ++i)
#pragma unroll
    for (int j = 0; j < 4; ++j) acc[i][j] = 0.f;

  for (int kc = 0; kc < IND; kc += 64) {
#pragma unroll
    for (int j = 0; j < 4; ++j) {
      int fi  = tid + 256 * j;       // 0..1023 float4 slots
      int row = fi >> 4;             // 0..63
      int c4  = fi & 15;             // float4 index within 64 k
      int id  = ids[t0 + row];
      id = max(0, min(id, VOCABN - 1));
      const float4 va = *(const float4*)(emb + (size_t)id * IND + kc + c4 * 4);
      As[c4 * 4 + 0][row] = va.x; As[c4 * 4 + 1][row] = va.y;
      As[c4 * 4 + 2][row] = va.z; As[c4 * 4 + 3][row] = va.w;
      const float4 vb = *(const float4*)(W_ih + (size_t)(n0 + row) * IND + kc + c4 * 4);
      Bs[c4 * 4 + 0][row] = vb.x; Bs[c4 * 4 + 1][row] = vb.y;
      Bs[c4 * 4 + 2][row] = vb.z; Bs[c4 * 4 + 3][row] = vb.w;
    }
    __syncthreads();
#pragma unroll 8
    for (int k = 0; k < 64; ++k) {
      const float4 a = *(const float4*)&As[k][tx * 4];
      const float4 b = *(const float4*)&Bs[k][ty * 4];
      acc[0][0] = fmaf(a.x, b.x, acc[0][0]); acc[0][1] = fmaf(a.x, b.y, acc[0][1]);
      acc[0][2] = fmaf(a.x, b.z, acc[0][2]); acc[0][3] = fmaf(a.x, b.w, acc[0][3]);
      acc[1][0] = fmaf(a.y, b.x, acc[1][0]); acc[1][1] = fmaf(a.y, b.y, acc[1][1]);
      acc[1][2] = fmaf(a.y, b.z, acc[1][2]); acc[1][3] = fmaf(a.y, b.w, acc[1][3]);
      acc[2][0] = fmaf(a.z, b.x, acc[2][0]); acc[2][1] = fmaf(a.z, b.y, acc[2][1]);
      acc[2][2] = fmaf(a.z, b.z, acc[2][2]); acc[2][3] = fmaf(a.z, b.w, acc[2][3]);
      acc[3][0] = fmaf(a.w, b.x, acc[3][0]); acc[3][1] = fmaf(a.w, b.y, acc[3][1]);
      acc[3][2] = fmaf(a.w, b.z, acc[3][2]); acc[3][3] = fmaf(a.w, b.w, acc[3][3]);
    }
    __syncthreads();
  }
#pragma unroll
  for (int ri = 0; ri < 4; ++ri) {
#pragma unroll
    for (int bj = 0; bj < 4; ++bj) {
      int t = t0 + tx * 4 + ri;
      int n = n0 + ty * 4 + bj;
      float v = acc[ri][bj] + b_ih[n] + b_hh[n];
      int w = (n & 511) >> 5;     // owning WG
      int gate = n >> 9;          // 0..3 (i,f,g,o)
      int hd = n & 31;            // local h dim
      int pos = w * 128 + gate * 32 + hd;
      xp[((size_t)s * SEQL + t) * G4 + pos] = f2bf(v);
    }
  }
}

// ---------- persistent recurrent kernel ----------
// 32 blocks x 512 threads. block -> (seq = blk&1, w = blk>>1).
// Wave 0 is the only poller (64 lanes x 8 coalesced words = one copy of h);
// h broadcast via stride-36-padded LDS (conflict-free, b128-readable).
// Wave 1 prefetches xp gate biases for step t+1 into a parity LDS stash.
__global__ __launch_bounds__(512) void lstm_rec(
    const float* __restrict__ W_hh,
    const unsigned short* __restrict__ xp,
    unsigned* __restrict__ hbuf) {
  __shared__ float hlds[16 * 36];     // 16 chunks of 32 h values, stride 36
  __shared__ float g_lds[128];
  __shared__ float xg_lds[2][128];
  const int blk = blockIdx.x;
  const int s = blk & 1;
  const int w = blk >> 1;          // 0..15
  const int tid = threadIdx.x;
  const int lane = tid & 63;
  const int wv = tid >> 6;         // wave id 0..7
  const int cg = tid & 15;         // k chunk group (32 k each)
  const int rg = tid >> 4;         // row group (4 rows each), 0..31

  // load W_hh slice into registers: rows r = rg*4+ri (local), k = cg*32..+32
  float wreg[4][32];
#pragma unroll
  for (int ri = 0; ri < 4; ++ri) {
    int r = rg * 4 + ri;           // 0..127
    int gate = r >> 5, hd = r & 31;
    const float* src = W_hh + ((size_t)gate * MEMD + w * 32 + hd) * MEMD + cg * 32;
#pragma unroll
    for (int q = 0; q < 8; ++q) {
      const float4 v = *(const float4*)(src + q * 4);
      wreg[ri][q * 4 + 0] = v.x; wreg[ri][q * 4 + 1] = v.y;
      wreg[ri][q * 4 + 2] = v.z; wreg[ri][q * 4 + 3] = v.w;
    }
  }

  unsigned* hbase = hbuf + s * (2 * MEMD);
  const unsigned short* xq0 = xp + (size_t)s * SEQL * G4 + w * 128;
  float cst = 0.f;                 // cell state (only tid<32 uses it)

  // preload xg stash for t=0
  if (wv == 1 && lane < 32) {
    xg_lds[0][lane]      = bf2f(xq0[lane]);
    xg_lds[0][32 + lane] = bf2f(xq0[32 + lane]);
    xg_lds[0][64 + lane] = bf2f(xq0[64 + lane]);
    xg_lds[0][96 + lane] = bf2f(xq0[96 + lane]);
  }

  for (int t = 0; t < SEQL; ++t) {
    // wave1: prefetch xp gate biases for step t+1 (parity double-buffered)
    if (wv == 1 && lane < 32 && t + 1 < SEQL) {
      const unsigned short* xq = xq0 + (size_t)(t + 1) * G4;
      float* dst = xg_lds[(t + 1) & 1];
      dst[lane]      = bf2f(xq[lane]);
      dst[32 + lane] = bf2f(xq[32 + lane]);
      dst[64 + lane] = bf2f(xq[64 + lane]);
      dst[96 + lane] = bf2f(xq[96 + lane]);
    }

    // wave0: poll h_t (epoch == t) — coalesced, exactly one copy of the vector
    if (wv == 0) {
      const unsigned* hr = hbase + (t & 1) * MEMD;
      unsigned v[8];
      const unsigned want = (unsigned)t;
      int guard = 0;
      for (;;) {
#pragma unroll
        for (int j = 0; j < 8; ++j)
          v[j] = __hip_atomic_load(hr + lane + 64 * j, __ATOMIC_RELAXED,
                                   __HIP_MEMORY_SCOPE_AGENT);
        bool good = true;
#pragma unroll
        for (int j = 0; j < 8; ++j) good &= ((v[j] >> 16) == want);
        if (__all(good)) break;
        if (++guard > (1 << 20)) break;   // safety valve: never hang the harness
      }
#pragma unroll
      for (int j = 0; j < 8; ++j) {
        int wj = lane + 64 * j;
        hlds[(wj >> 5) * 36 + (wj & 31)] = bf2f(v[j] & 0xffffu);
      }
    }
    __syncthreads();

    // ---- all threads: load h chunk (b128, conflict-free) & dot products ----
    float hreg[32];
#pragma unroll
    for (int q = 0; q < 8; ++q) {
      const float4 hv = *(const float4*)&hlds[cg * 36 + q * 4];
      hreg[q * 4 + 0] = hv.x; hreg[q * 4 + 1] = hv.y;
      hreg[q * 4 + 2] = hv.z; hreg[q * 4 + 3] = hv.w;
    }
    float part[4] = {0.f, 0.f, 0.f, 0.f};
#pragma unroll
    for (int kk = 0; kk < 32; ++kk) {
#pragma unroll
      for (int ri = 0; ri < 4; ++ri)
        part[ri] = fmaf(wreg[ri][kk], hreg[kk], part[ri]);
    }
#pragma unroll
    for (int m = 8; m >= 1; m >>= 1) {
#pragma unroll
      for (int ri = 0; ri < 4; ++ri)
        part[ri] += __shfl_xor(part[ri], m, 64);
    }
    if (cg == 0) {
#pragma unroll
      for (int ri = 0; ri < 4; ++ri) g_lds[rg * 4 + ri] = part[ri];
    }
    __syncthreads();

    // ---- gate math + publish h_{t+1} (wave0 lanes 0..31) ----
    if (tid < 32) {
      const float* xg = xg_lds[t & 1];
      float gi = g_lds[tid]      + xg[tid];
      float gf = g_lds[32 + tid] + xg[32 + tid];
      float gg = g_lds[64 + tid] + xg[64 + tid];
      float go = g_lds[96 + tid] + xg[96 + tid];
      float i_ = 1.f / (1.f + __expf(-gi));
      float f_ = 1.f / (1.f + __expf(-gf));
      float ggc = fminf(fmaxf(gg, -15.f), 15.f);
      float e2 = __expf(-2.f * ggc);
      float g_ = (1.f - e2) / (1.f + e2);
      float o_ = 1.f / (1.f + __expf(-go));
      cst = f_ * cst + i_ * g_;
      float cc = fminf(fmaxf(cst, -15.f), 15.f);
      float e2c = __expf(-2.f * cc);
      float th = (1.f - e2c) / (1.f + e2c);
      float h_ = o_ * th;
      unsigned word = (((unsigned)(t + 1)) << 16) | (unsigned)f2bf(h_);
      __hip_atomic_store(hbase + ((t + 1) & 1) * MEMD + w * 32 + tid, word,
                         __ATOMIC_RELAXED, __HIP_MEMORY_SCOPE_AGENT);
    }
  }
}

// ---------- final reduction: out = exp(-sum |lh - rh|) ----------
__global__ __launch_bounds__(512) void finish_k(const unsigned* __restrict__ hbuf,
                                                float* __restrict__ out) {
  const int tid = threadIdx.x;   // epoch 2048 lives in the parity-0 buffers
  float l = bf2f(hbuf[tid] & 0xffffu);
  float r = bf2f(hbuf[2 * MEMD + tid] & 0xffffu);
  float d = fabsf(l - r);
#pragma unroll
  for (int m = 32; m >= 1; m >>= 1) d += __shfl_xor(d, m, 64);
  __shared__ float wsum[8];
  if ((tid & 63) == 0) wsum[tid >> 6] = d;
  __syncthreads();
  if (tid == 0) {
    float sum = 0.f;
#pragma unroll
    for (int i = 0; i < 8; ++i) sum += wsum[i];
    out[0] = expf(-sum);
  }
}

extern "C" void kernel_launch(void* const* d_in, const int* in_sizes, int n_in,
                              void* d_out, int out_size, void* d_ws, size_t ws_size,
                              hipStream_t stream) {
  const int*   lin  = (const int*)d_in[0];
  const int*   rin  = (const int*)d_in[1];
  const float* emb  = (const float*)d_in[2];
  const float* W_ih = (const float*)d_in[3];
  const float* W_hh = (const float*)d_in[4];
  const float* b_ih = (const float*)d_in[5];
  const float* b_hh = (const float*)d_in[6];
  float* out = (float*)d_out;

  unsigned char* ws = (unsigned char*)d_ws;
  unsigned short* xp = (unsigned short*)ws;
  unsigned* hbuf = (unsigned*)(ws + (size_t)2 * SEQL * G4 * sizeof(unsigned short));

  hipLaunchKernelGGL(init_k, dim3(2), dim3(1024), 0, stream, hbuf);
  hipLaunchKernelGGL(xp_gemm, dim3(SEQL / 64, G4 / 64, 2), dim3(256), 0, stream,
                     lin, rin, emb, W_ih, b_ih, b_hh, xp);
  hipLaunchKernelGGL(lstm_rec, dim3(2 * NWG), dim3(512), 0, stream, W_hh, xp, hbuf);
  hipLaunchKernelGGL(finish_k, dim3(1), dim3(512), 0, stream, hbuf, out);
}